// Round 2
// baseline (379.266 us; speedup 1.0000x reference)
//
#include <hip/hip_runtime.h>

#define S_ 1024
#define H_ 16
#define D_ 32

typedef float f32x4 __attribute__((ext_vector_type(4)));
typedef short bf16x8 __attribute__((ext_vector_type(8)));

static __device__ __forceinline__ short f2b(float f) {
    union { float f; unsigned u; } x; x.f = f;
    unsigned u = x.u;
    unsigned r = u + 0x7fffu + ((u >> 16) & 1u);
    if ((u & 0x7f800000u) == 0x7f800000u && (u & 0x007fffffu)) r = u; // NaN passthrough
    return (short)(r >> 16);
}
static __device__ __forceinline__ float b2f(short s) {
    union { unsigned u; float f; } x; x.u = ((unsigned)(unsigned short)s) << 16;
    return x.f;
}
// pack two fp32 -> bf16x2 dword (lo in low half), round-to-nearest-even (no NaN guard)
static __device__ __forceinline__ unsigned pk_rne(float lo, float hi) {
    union { float f; unsigned u; } a, b; a.f = lo; b.f = hi;
    unsigned ul = a.u + 0x7fffu + ((a.u >> 16) & 1u);
    unsigned uh = b.u + 0x7fffu + ((b.u >> 16) & 1u);
    return __builtin_amdgcn_perm(uh, ul, 0x07060302u);
}
// truncating pack (1 VALU) — used only for P in [0,1]
static __device__ __forceinline__ unsigned pk_trunc(float lo, float hi) {
    union { float f; unsigned u; } a, b; a.f = lo; b.f = hi;
    return __builtin_amdgcn_perm(b.u, a.u, 0x07060302u);
}

// ---------------- prep: rel_table fp32->bf16 + mask bit-pack ----------------
__global__ __launch_bounds__(256)
void prep_kernel(const float* __restrict__ rt, short* __restrict__ relb,
                 const int* __restrict__ mask, unsigned long long* __restrict__ mbits)
{
    int bid = blockIdx.x;
    int t = threadIdx.x;
    if (bid < 257) {
        int i = bid * 256 + t;
        if (i < 2049 * 32) relb[i] = f2b(rt[i]);
    } else {
        int i = (bid - 257) * 256 + t;                 // element into 4M mask
        unsigned long long bal = __ballot(mask[i] > 0);
        if ((t & 63) == 0) mbits[i >> 6] = bal;
    }
}

// ---------------- MFMA GEMM: [4096x512] @ [512x512] ----------------
// MODE 0: out fp32 plain [m][n]
// MODE 1: out bf16 heads  [b][h][s][d]
// MODE 2: out bf16 headsT [b][h][d][s'] with s' k-permuted within 64-groups for PV
template<int MODE, bool ABF16>
__global__ __launch_bounds__(256)
void gemm_mfma(const void* __restrict__ Avoid, const float* __restrict__ W,
               void* __restrict__ out, float alpha)
{
    __shared__ __align__(16) short a_s[128 * 40];
    __shared__ __align__(16) short b_s[64 * 40];
    const int t = threadIdx.x;
    const int w = t >> 6, lane = t & 63, l15 = lane & 15, quad = lane >> 4;
    const int wm = w & 1, wn = w >> 1;
    const int bm = blockIdx.y * 128, bn = blockIdx.x * 64;

    f32x4 acc[4][2] = {};

    for (int k0 = 0; k0 < 512; k0 += 32) {
        if constexpr (!ABF16) {
            const float* A = (const float*)Avoid;
            #pragma unroll
            for (int i = 0; i < 4; ++i) {
                int lin = t + i * 256;
                int r = lin >> 3, c4 = (lin & 7) * 4;
                float4 v = *(const float4*)(A + (long)(bm + r) * 512 + k0 + c4);
                unsigned long long pv = ((unsigned long long)pk_rne(v.z, v.w) << 32) |
                                        (unsigned long long)pk_rne(v.x, v.y);
                *(unsigned long long*)(a_s + r * 40 + c4) = pv;
            }
        } else {
            const short* A = (const short*)Avoid;
            #pragma unroll
            for (int i = 0; i < 2; ++i) {
                int lin = t + i * 256;
                int r = lin >> 2, c8 = (lin & 3) * 8;
                bf16x8 v = *(const bf16x8*)(A + (long)(bm + r) * 512 + k0 + c8);
                *(bf16x8*)(a_s + r * 40 + c8) = v;
            }
        }
        // W tile transposed to b_s[n][k], vectorized loads
        #pragma unroll
        for (int i = 0; i < 2; ++i) {
            int lin = t + i * 256;                    // 0..511
            int kr = lin >> 4, nc = (lin & 15) * 4;
            float4 v = *(const float4*)(W + (long)(k0 + kr) * 512 + bn + nc);
            b_s[(nc + 0) * 40 + kr] = f2b(v.x);
            b_s[(nc + 1) * 40 + kr] = f2b(v.y);
            b_s[(nc + 2) * 40 + kr] = f2b(v.z);
            b_s[(nc + 3) * 40 + kr] = f2b(v.w);
        }
        __syncthreads();

        bf16x8 af[4], bfr[2];
        #pragma unroll
        for (int mt = 0; mt < 4; ++mt)
            af[mt] = *(const bf16x8*)(a_s + (wm * 64 + mt * 16 + l15) * 40 + quad * 8);
        #pragma unroll
        for (int nt = 0; nt < 2; ++nt)
            bfr[nt] = *(const bf16x8*)(b_s + (wn * 32 + nt * 16 + l15) * 40 + quad * 8);
        #pragma unroll
        for (int mt = 0; mt < 4; ++mt)
            #pragma unroll
            for (int nt = 0; nt < 2; ++nt)
                acc[mt][nt] = __builtin_amdgcn_mfma_f32_16x16x32_bf16(af[mt], bfr[nt], acc[mt][nt], 0, 0, 0);
        __syncthreads();
    }

    #pragma unroll
    for (int mt = 0; mt < 4; ++mt) {
        #pragma unroll
        for (int nt = 0; nt < 2; ++nt) {
            #pragma unroll
            for (int r = 0; r < 4; ++r) {
                int m = bm + wm * 64 + mt * 16 + quad * 4 + r;
                int n = bn + wn * 32 + nt * 16 + l15;
                float v = acc[mt][nt][r] * alpha;
                if constexpr (MODE == 0) {
                    ((float*)out)[(long)m * 512 + n] = v;
                } else if constexpr (MODE == 1) {
                    int bb = m >> 10, s = m & 1023, hh = n >> 5, dd = n & 31;
                    ((short*)out)[((long)((bb * 16 + hh) * 1024 + s)) * 32 + dd] = f2b(v);
                } else {
                    int bb = m >> 10, s = m & 1023, hh = n >> 5, dd = n & 31;
                    int sp = (s & ~63) | ((s & 15) << 2) | ((s >> 4) & 3); // k-permute
                    ((short*)out)[((long)((bb * 16 + hh) * 32 + dd)) * 1024 + sp] = f2b(v);
                }
            }
        }
    }
}

// ---------------- QR = Wrel @ qh per row ----------------
__global__ __launch_bounds__(256)
void qr_kernel(const short* __restrict__ qh, const float* __restrict__ wrel,
               short* __restrict__ qr)
{
    __shared__ float ws[32 * 33];
    __shared__ float qs[8 * 32];
    int t = threadIdx.x;
    for (int i = t; i < 1024; i += 256) ws[(i >> 5) * 33 + (i & 31)] = wrel[i];
    long row0 = (long)blockIdx.x * 8;
    int rloc = t >> 5, io = t & 31;
    qs[rloc * 32 + io] = b2f(qh[(row0 + rloc) * 32 + io]);
    __syncthreads();
    float acc = 0.f;
    #pragma unroll
    for (int j = 0; j < 32; ++j) acc += ws[io * 33 + j] * qs[rloc * 32 + j];
    qr[(row0 + rloc) * 32 + io] = f2b(acc);
}

// ---------------- fused attention v2: one wave = one (b,h,16-q tile) ----------------
// online softmax over 16 chunks of 64 k; wave-private LDS; no __syncthreads.
__global__ __launch_bounds__(256)
void attn_kernel(const short* __restrict__ qh, const short* __restrict__ qr,
                 const short* __restrict__ kh, const short* __restrict__ vt,
                 const short* __restrict__ relb, const unsigned long long* __restrict__ mbits,
                 short* __restrict__ ao)
{
    __shared__ __align__(16) char smem[4 * 7680];
    const int t = threadIdx.x;
    const int w = t >> 6, lane = t & 63, l15 = lane & 15, quad = lane >> 4;
    float* ctw = (float*)(smem + w * 7680);            // [16 q][80 u'] f32, pitch 84
    short* pw  = (short*)(smem + w * 7680 + 5376);     // [16 q][64 k'] bf16, pitch 72

    const int gw = blockIdx.x * 4 + w;
    const int qt = gw & 63, h = (gw >> 6) & 15, b = gw >> 10;
    const int q0 = qt * 16, bh = b * H_ + h;

    const long qbase = ((long)bh * S_ + q0 + l15) * D_ + quad * 8;
    const bf16x8 a_qh = *(const bf16x8*)(qh + qbase);
    const bf16x8 a_qr = *(const bf16x8*)(qr + qbase);
    const long kv_bh = (long)bh * S_ * D_;
    const unsigned long long* mrow = mbits + ((long)b * S_ + q0 + quad * 4) * 16;

    f32x4 oacc[2] = {};
    float m4[4], l4[4] = {0.f, 0.f, 0.f, 0.f};
    #pragma unroll
    for (int r = 0; r < 4; ++r) m4[r] = -__builtin_inff();

    for (int c = 0; c < 16; ++c) {
        const int kbase = c * 64;
        const int ub = kbase - q0 + (S_ - 15);         // table row base, >= 1
        asm volatile("s_waitcnt lgkmcnt(0)" ::: "memory"); // prev-iter LDS reads drained

        // rel bias tiles -> ctw, u-permuted: u = ut*16+l15 stored at u' = l15*5+ut
        #pragma unroll
        for (int ut = 0; ut < 5; ++ut) {
            bf16x8 bre = *(const bf16x8*)(relb + (long)(ub + ut * 16 + l15) * D_ + quad * 8);
            f32x4 z = {0.f, 0.f, 0.f, 0.f};
            f32x4 ct = __builtin_amdgcn_mfma_f32_16x16x32_bf16(a_qr, bre, z, 0, 0, 0);
            #pragma unroll
            for (int r = 0; r < 4; ++r)
                ctw[(quad * 4 + r) * 84 + l15 * 5 + ut] = ct[r];
        }
        // QK^T for this chunk
        f32x4 sc[4];
        #pragma unroll
        for (int kt = 0; kt < 4; ++kt) {
            bf16x8 bk = *(const bf16x8*)(kh + kv_bh + (long)(kbase + kt * 16 + l15) * D_ + quad * 8);
            f32x4 z = {0.f, 0.f, 0.f, 0.f};
            sc[kt] = __builtin_amdgcn_mfma_f32_16x16x32_bf16(a_qh, bk, z, 0, 0, 0);
        }
        asm volatile("s_waitcnt lgkmcnt(0)" ::: "memory"); // ctw visible

        // add rel bias (4 contiguous dwords thanks to u-permute), row max
        float mnew[4];
        #pragma unroll
        for (int r = 0; r < 4; ++r) {
            int qq = quad * 4 + r;
            int uu = 15 - qq + l15;                    // 0..30
            const float* cb = ctw + qq * 84 + (uu & 15) * 5 + (uu >> 4);
            float s0 = sc[0][r] + cb[0];
            float s1 = sc[1][r] + cb[1];
            float s2 = sc[2][r] + cb[2];
            float s3 = sc[3][r] + cb[3];
            sc[0][r] = s0; sc[1][r] = s1; sc[2][r] = s2; sc[3][r] = s3;
            float mx = fmaxf(fmaxf(s0, s1), fmaxf(s2, s3));
            mx = fmaxf(mx, __shfl_xor(mx, 1, 64));
            mx = fmaxf(mx, __shfl_xor(mx, 2, 64));
            mx = fmaxf(mx, __shfl_xor(mx, 4, 64));
            mx = fmaxf(mx, __shfl_xor(mx, 8, 64));
            mnew[r] = fmaxf(m4[r], mx);
        }
        // rescale, exp, mask (post-exp multiply), pack P k-permuted
        #pragma unroll
        for (int r = 0; r < 4; ++r) {
            float alpha = __expf(m4[r] - mnew[r]);
            m4[r] = mnew[r];
            l4[r] *= alpha;
            oacc[0][r] *= alpha;
            oacc[1][r] *= alpha;
            unsigned long long mw = mrow[r * 16 + c] >> l15;
            unsigned lo = (unsigned)mw, hi = (unsigned)(mw >> 32);
            float p0 = __expf(sc[0][r] - mnew[r]); p0 = (lo & 1u)        ? p0 : 0.f;
            float p1 = __expf(sc[1][r] - mnew[r]); p1 = ((lo >> 16) & 1u) ? p1 : 0.f;
            float p2 = __expf(sc[2][r] - mnew[r]); p2 = (hi & 1u)        ? p2 : 0.f;
            float p3 = __expf(sc[3][r] - mnew[r]); p3 = ((hi >> 16) & 1u) ? p3 : 0.f;
            l4[r] += p0 + p1 + p2 + p3;
            unsigned long long pv = ((unsigned long long)pk_trunc(p2, p3) << 32) |
                                    (unsigned long long)pk_trunc(p0, p1);
            *(unsigned long long*)(pw + (quad * 4 + r) * 72 + l15 * 4) = pv;
        }
        asm volatile("s_waitcnt lgkmcnt(0)" ::: "memory"); // pw visible

        // PV with k-permuted A (pw) and matching k-permuted V^T
        #pragma unroll
        for (int ks = 0; ks < 2; ++ks) {
            bf16x8 ap = *(const bf16x8*)(pw + l15 * 72 + ks * 32 + quad * 8);
            #pragma unroll
            for (int dt = 0; dt < 2; ++dt) {
                bf16x8 bv = *(const bf16x8*)(vt + kv_bh + (long)(dt * 16 + l15) * S_ + kbase + ks * 32 + quad * 8);
                oacc[dt] = __builtin_amdgcn_mfma_f32_16x16x32_bf16(ap, bv, oacc[dt], 0, 0, 0);
            }
        }
    }

    // epilogue: reduce row sums across the 16-lane group, normalize, store
    #pragma unroll
    for (int r = 0; r < 4; ++r) {
        float l = l4[r];
        l += __shfl_xor(l, 1, 64);
        l += __shfl_xor(l, 2, 64);
        l += __shfl_xor(l, 4, 64);
        l += __shfl_xor(l, 8, 64);
        float inv = 1.0f / l;
        int row = q0 + quad * 4 + r;
        #pragma unroll
        for (int dt = 0; dt < 2; ++dt)
            ao[((long)(b * S_ + row) * H_ + h) * D_ + dt * 16 + l15] = f2b(oacc[dt][r] * inv);
    }
}

extern "C" void kernel_launch(void* const* d_in, const int* in_sizes, int n_in,
                              void* d_out, int out_size, void* d_ws, size_t ws_size,
                              hipStream_t stream) {
    (void)in_sizes; (void)n_in; (void)out_size; (void)ws_size;
    const float* kv   = (const float*)d_in[0];
    const float* q    = (const float*)d_in[1];
    const int*   mask = (const int*)d_in[2];
    const float* Wq   = (const float*)d_in[3];
    const float* Wk   = (const float*)d_in[4];
    const float* Wv   = (const float*)d_in[5];
    const float* Wo   = (const float*)d_in[6];
    const float* rt   = (const float*)d_in[7];
    const float* Wrel = (const float*)d_in[8];

    char* ws = (char*)d_ws;
    short* qh   = (short*)(ws);                      // [B,H,S,D] bf16, 4MB each
    short* kh   = (short*)(ws + (4u  << 20));
    short* vt   = (short*)(ws + (8u  << 20));        // [B,H,D,S'] k-permuted
    short* qr   = (short*)(ws + (12u << 20));
    short* ao   = (short*)(ws + (16u << 20));        // [B,S,H,D]
    short* relb = (short*)(ws + (20u << 20));        // [2049,32] bf16
    unsigned long long* mbits = (unsigned long long*)(ws + (20u << 20) + (256u << 10));

    prep_kernel<<<257 + 16384, 256, 0, stream>>>(rt, relb, mask, mbits);

    dim3 gg(8, 32); // N/64, M/128
    const float scale = 0.17677669529663687f;        // 1/sqrt(32) folded into QH (and QR)
    gemm_mfma<1, false><<<gg, 256, 0, stream>>>(q,  Wq, qh, scale);
    gemm_mfma<1, false><<<gg, 256, 0, stream>>>(kv, Wk, kh, 1.0f);
    gemm_mfma<2, false><<<gg, 256, 0, stream>>>(kv, Wv, vt, 1.0f);

    qr_kernel<<<8192, 256, 0, stream>>>(qh, Wrel, qr);

    attn_kernel<<<1024, 256, 0, stream>>>(qh, qr, kh, vt, relb, mbits, ao);

    gemm_mfma<0, true><<<gg, 256, 0, stream>>>(ao, Wo, d_out, 1.0f);
}

// Round 5
// 202.383 us; speedup vs baseline: 1.8740x; 1.8740x over previous
//
#include <hip/hip_runtime.h>

#define S_ 1024
#define H_ 16
#define D_ 32

typedef float f32x4 __attribute__((ext_vector_type(4)));
typedef short bf16x8 __attribute__((ext_vector_type(8)));
typedef unsigned long long u64;

static __device__ __forceinline__ short f2b(float f) {
    union { float f; unsigned u; } x; x.f = f;
    unsigned u = x.u;
    unsigned r = u + 0x7fffu + ((u >> 16) & 1u);
    return (short)(r >> 16);
}
static __device__ __forceinline__ unsigned pk_rne(float lo, float hi) {
    union { float f; unsigned u; } a, b; a.f = lo; b.f = hi;
    unsigned ul = a.u + 0x7fffu + ((a.u >> 16) & 1u);
    unsigned uh = b.u + 0x7fffu + ((b.u >> 16) & 1u);
    return __builtin_amdgcn_perm(uh, ul, 0x07060302u);
}
static __device__ __forceinline__ unsigned pk_trunc(float lo, float hi) {
    union { float f; unsigned u; } a, b; a.f = lo; b.f = hi;
    return __builtin_amdgcn_perm(b.u, a.u, 0x07060302u);
}
static __device__ __forceinline__ float bperm(int bidx, float v) {
    union { float f; int i; } x; x.f = v;
    x.i = __builtin_amdgcn_ds_bpermute(bidx, x.i);
    return x.f;
}
// LDS staging offset with XOR swizzle (c8 in units of shorts, multiple of 8)
static __device__ __forceinline__ int stg(int row, int c8) {
    return row * 40 + (c8 ^ ((row & 3) << 3));
}

// ---------------- prep: relb cvt + mask pack + W transpose ----------------
__global__ __launch_bounds__(256)
void prep_kernel(const float* __restrict__ rt, short* __restrict__ relb,
                 const int* __restrict__ mask, u64* __restrict__ mbits,
                 const float* __restrict__ Wq, const float* __restrict__ Wk,
                 const float* __restrict__ Wv, const float* __restrict__ Wo,
                 short* __restrict__ Wt)
{
    __shared__ float ls[32][33];
    int bid = blockIdx.x, t = threadIdx.x;
    if (bid < 257) {                                   // rel_table -> bf16 (65568 elems)
        int i = bid * 256 + t;
        if (i < 2049 * 32) relb[i] = f2b(rt[i]);
        return;
    }
    bid -= 257;
    if (bid < 4096) {                                  // mask bit-pack (4M ints -> 64K u64)
        #pragma unroll
        for (int j = 0; j < 4; ++j) {
            int i = bid * 1024 + j * 256 + t;
            u64 bal = __ballot(mask[i] > 0);
            if ((t & 63) == 0) mbits[i >> 6] = bal;
        }
        return;
    }
    bid -= 4096;                                       // W transpose -> bf16 [mat][n][k], 1024 blocks
    int mat = bid >> 8, tl = bid & 255, ti = tl >> 4, tj = tl & 15;
    const float* W = (mat == 0) ? Wq : (mat == 1) ? Wk : (mat == 2) ? Wv : Wo;
    int r = t >> 3, c = (t & 7) * 4;
    float4 v = *(const float4*)(W + (long)(ti * 32 + r) * 512 + tj * 32 + c);
    ls[r][c] = v.x; ls[r][c + 1] = v.y; ls[r][c + 2] = v.z; ls[r][c + 3] = v.w;
    __syncthreads();
    int nl = t >> 3, kk = (t & 7) * 4;
    uint2 o = { pk_rne(ls[kk][nl], ls[kk + 1][nl]),
                pk_rne(ls[kk + 2][nl], ls[kk + 3][nl]) };
    *(uint2*)(Wt + ((long)mat * 512 + tj * 32 + nl) * 512 + ti * 32 + kk) = o;
}

// ---------------- fused projection GEMMs: qh, kh, vt (64x64 tiles, fp32 A inline-cvt) ----------------
__global__ __launch_bounds__(256)
void gemm3_kernel(const float* __restrict__ q, const float* __restrict__ kv,
                  const short* __restrict__ Wt,
                  short* __restrict__ qh, short* __restrict__ kh, short* __restrict__ vt,
                  float scale)
{
    __shared__ __align__(16) short a_s[64 * 40];
    __shared__ __align__(16) short b_s[64 * 40];
    const int t = threadIdx.x;
    const int w = t >> 6, lane = t & 63, l15 = lane & 15, quad = lane >> 4;
    const int wm = w & 1, wn = w >> 1;

    int bid = blockIdx.x;
    const int mat = bid >> 9;                  // 0:q@Wq 1:kv@Wk 2:kv@Wv
    const int rr_ = bid & 511;
    const int bm = (rr_ >> 3) * 64, bn = (rr_ & 7) * 64;
    const float* A = (mat == 0) ? q : kv;
    const short* Wm = Wt + (long)mat * 262144;

    const int srow = t >> 2, sc8 = (t & 3) << 3;
    f32x4 acc[2][2] = {};

    for (int k0 = 0; k0 < 512; k0 += 32) {
        // stage A (fp32 -> bf16) and W (bf16) tiles
        {
            const float* ap = A + (long)(bm + srow) * 512 + k0 + sc8;
            float4 v0 = *(const float4*)(ap);
            float4 v1 = *(const float4*)(ap + 4);
            uint4 o = { pk_rne(v0.x, v0.y), pk_rne(v0.z, v0.w),
                        pk_rne(v1.x, v1.y), pk_rne(v1.z, v1.w) };
            *(uint4*)(a_s + stg(srow, sc8)) = o;
        }
        *(bf16x8*)(b_s + stg(srow, sc8)) = *(const bf16x8*)(Wm + (long)(bn + srow) * 512 + k0 + sc8);
        __syncthreads();
        bf16x8 af[2], bfr[2];
        #pragma unroll
        for (int i = 0; i < 2; ++i) {
            af[i]  = *(const bf16x8*)(a_s + stg(wm * 32 + i * 16 + l15, quad * 8));
            bfr[i] = *(const bf16x8*)(b_s + stg(wn * 32 + i * 16 + l15, quad * 8));
        }
        if (mat == 2) {
            #pragma unroll
            for (int i = 0; i < 2; ++i)
                #pragma unroll
                for (int j = 0; j < 2; ++j)
                    acc[i][j] = __builtin_amdgcn_mfma_f32_16x16x32_bf16(bfr[i], af[j], acc[i][j], 0, 0, 0);
        } else {
            #pragma unroll
            for (int i = 0; i < 2; ++i)
                #pragma unroll
                for (int j = 0; j < 2; ++j)
                    acc[i][j] = __builtin_amdgcn_mfma_f32_16x16x32_bf16(af[i], bfr[j], acc[i][j], 0, 0, 0);
        }
        __syncthreads();
    }

    if (mat < 2) {
        short* out = (mat == 0) ? qh : kh;
        float alpha = (mat == 0) ? scale : 1.0f;
        #pragma unroll
        for (int i = 0; i < 2; ++i)
            #pragma unroll
            for (int j = 0; j < 2; ++j)
                #pragma unroll
                for (int r = 0; r < 4; ++r) {
                    int m = bm + wm * 32 + i * 16 + quad * 4 + r;
                    int n = bn + wn * 32 + j * 16 + l15;
                    int bb = m >> 10, s = m & 1023, hh = n >> 5, dd = n & 31;
                    out[((long)((bb * 16 + hh) * 1024 + s)) * 32 + dd] = f2b(acc[i][j][r] * alpha);
                }
    } else {
        // operand-swapped: acc holds C^T (row = feature, col = token)
        #pragma unroll
        for (int i = 0; i < 2; ++i)
            #pragma unroll
            for (int j = 0; j < 2; ++j)
                #pragma unroll
                for (int r = 0; r < 4; ++r) {
                    int n = bn + wn * 32 + i * 16 + quad * 4 + r;   // feature (h,d)
                    int m = bm + wm * 32 + j * 16 + l15;            // token
                    int bb = m >> 10, s = m & 1023, hh = n >> 5, dd = n & 31;
                    int sp = (s & ~63) | ((s & 15) << 2) | ((s >> 4) & 3); // k-permute
                    vt[((long)((bb * 16 + hh) * 32 + dd)) * 1024 + sp] = f2b(acc[i][j][r]);
                }
    }
}

// ---------------- output GEMM: d_out = ao @ Wo ----------------
__global__ __launch_bounds__(256)
void gemm_out_kernel(const short* __restrict__ ao, const short* __restrict__ Wt,
                     float* __restrict__ out)
{
    __shared__ __align__(16) short a_s[64 * 40];
    __shared__ __align__(16) short b_s[64 * 40];
    const int t = threadIdx.x;
    const int w = t >> 6, lane = t & 63, l15 = lane & 15, quad = lane >> 4;
    const int wm = w & 1, wn = w >> 1;
    const int bm = (blockIdx.x >> 3) * 64, bn = (blockIdx.x & 7) * 64;
    const short* Wm = Wt + (long)3 * 262144;
    const int srow = t >> 2, sc8 = (t & 3) << 3;
    f32x4 acc[2][2] = {};

    for (int k0 = 0; k0 < 512; k0 += 32) {
        *(bf16x8*)(a_s + stg(srow, sc8)) = *(const bf16x8*)(ao + (long)(bm + srow) * 512 + k0 + sc8);
        *(bf16x8*)(b_s + stg(srow, sc8)) = *(const bf16x8*)(Wm + (long)(bn + srow) * 512 + k0 + sc8);
        __syncthreads();
        bf16x8 af[2], bfr[2];
        #pragma unroll
        for (int i = 0; i < 2; ++i) {
            af[i]  = *(const bf16x8*)(a_s + stg(wm * 32 + i * 16 + l15, quad * 8));
            bfr[i] = *(const bf16x8*)(b_s + stg(wn * 32 + i * 16 + l15, quad * 8));
        }
        #pragma unroll
        for (int i = 0; i < 2; ++i)
            #pragma unroll
            for (int j = 0; j < 2; ++j)
                acc[i][j] = __builtin_amdgcn_mfma_f32_16x16x32_bf16(af[i], bfr[j], acc[i][j], 0, 0, 0);
        __syncthreads();
    }
    #pragma unroll
    for (int i = 0; i < 2; ++i)
        #pragma unroll
        for (int j = 0; j < 2; ++j)
            #pragma unroll
            for (int r = 0; r < 4; ++r) {
                int m = bm + wm * 32 + i * 16 + quad * 4 + r;
                int n = bn + wn * 32 + j * 16 + l15;
                out[(long)m * 512 + n] = acc[i][j][r];
            }
}

// ---------------- fused attention: wave-autonomous, register rel-bias, inline QR ----------------
__global__ __launch_bounds__(256, 4)
void attn_kernel(const short* __restrict__ qh, const float* __restrict__ wrel,
                 const short* __restrict__ kh, const short* __restrict__ vt,
                 const short* __restrict__ relb, const u64* __restrict__ mbits,
                 short* __restrict__ ao)
{
    __shared__ __align__(16) short smem[4 * 2 * 16 * 72];
    const int t = threadIdx.x;
    const int w = t >> 6, lane = t & 63, l15 = lane & 15, quad = lane >> 4;
    short* pw0 = smem + w * (2 * 16 * 72);
    short* pw1 = pw0 + 16 * 72;

    const int gw = blockIdx.x * 4 + w;
    const int qt = gw & 63, h = (gw >> 6) & 15, b = gw >> 10;
    const int q0 = qt * 16, bh = b * H_ + h;

    const long qbase = ((long)bh * S_ + q0 + l15) * D_ + quad * 8;
    const bf16x8 a_qh = *(const bf16x8*)(qh + qbase);
    const long kv_bh = (long)bh * S_ * D_;
    const u64* mrow = mbits + ((long)b * S_ + q0 + quad * 4) * 16;

    // ---- inline QR: qr[q][d] = sum_k qh[q][k] * Wrel[d][k]  (2 MFMAs + LDS transpose) ----
    bf16x8 a_qr;
    {
        #pragma unroll
        for (int nt = 0; nt < 2; ++nt) {
            const float* wp = wrel + (long)(nt * 16 + l15) * 32 + quad * 8;
            float4 w0 = *(const float4*)(wp);
            float4 w1 = *(const float4*)(wp + 4);
            bf16x8 bw;
            *(uint4*)&bw = (uint4){ pk_rne(w0.x, w0.y), pk_rne(w0.z, w0.w),
                                    pk_rne(w1.x, w1.y), pk_rne(w1.z, w1.w) };
            f32x4 z = {0.f, 0.f, 0.f, 0.f};
            f32x4 cq = __builtin_amdgcn_mfma_f32_16x16x32_bf16(a_qh, bw, z, 0, 0, 0);
            #pragma unroll
            for (int r = 0; r < 4; ++r)
                pw0[(quad * 4 + r) * 36 + nt * 16 + l15] = f2b(cq[r]);
        }
        asm volatile("" ::: "memory");                 // keep writes before read
        a_qr = *(const bf16x8*)(pw0 + l15 * 36 + quad * 8);
        asm volatile("" ::: "memory");                 // keep read before pw0 reuse
    }

    // bias shuffle indices: for row qq, lane l15 needs ct value from lane ((l15+15-qq)&15)
    int bidx[4]; int cnd[4];
    #pragma unroll
    for (int r = 0; r < 4; ++r) {
        int qq = quad * 4 + r;
        bidx[r] = (quad * 16 + ((l15 + 15 - qq) & 15)) * 4;
        cnd[r] = (l15 > qq);
    }

    f32x4 oacc[2] = {};
    float m4[4], l4[4] = {0.f, 0.f, 0.f, 0.f};
    #pragma unroll
    for (int r = 0; r < 4; ++r) m4[r] = -__builtin_inff();

    bf16x8 preg0 = {}, preg1 = {};
    bf16x8 bv00 = {}, bv01 = {}, bv10 = {}, bv11 = {};  // [ks][dt]

    for (int c = 0; c < 16; ++c) {
        const int kbase = c * 64;
        const int ub = kbase - q0 + (S_ - 15);
        short* pwbuf = (c & 1) ? pw1 : pw0;

        // rel + QK MFMAs (9 independent)
        f32x4 ctf[5], sc[4];
        #pragma unroll
        for (int ut = 0; ut < 5; ++ut) {
            bf16x8 bre = *(const bf16x8*)(relb + (long)(ub + ut * 16 + l15) * D_ + quad * 8);
            f32x4 z = {0.f, 0.f, 0.f, 0.f};
            ctf[ut] = __builtin_amdgcn_mfma_f32_16x16x32_bf16(a_qr, bre, z, 0, 0, 0);
        }
        #pragma unroll
        for (int kt = 0; kt < 4; ++kt) {
            bf16x8 bk = *(const bf16x8*)(kh + kv_bh + (long)(kbase + kt * 16 + l15) * D_ + quad * 8);
            f32x4 z = {0.f, 0.f, 0.f, 0.f};
            sc[kt] = __builtin_amdgcn_mfma_f32_16x16x32_bf16(a_qh, bk, z, 0, 0, 0);
        }
        // PV for previous chunk (P and V already in regs)
        if (c) {
            oacc[0] = __builtin_amdgcn_mfma_f32_16x16x32_bf16(preg0, bv00, oacc[0], 0, 0, 0);
            oacc[1] = __builtin_amdgcn_mfma_f32_16x16x32_bf16(preg0, bv01, oacc[1], 0, 0, 0);
            oacc[0] = __builtin_amdgcn_mfma_f32_16x16x32_bf16(preg1, bv10, oacc[0], 0, 0, 0);
            oacc[1] = __builtin_amdgcn_mfma_f32_16x16x32_bf16(preg1, bv11, oacc[1], 0, 0, 0);
        }
        // prefetch V for this chunk (consumed next iteration / epilogue)
        bv00 = *(const bf16x8*)(vt + kv_bh + (long)(l15) * S_ + kbase + quad * 8);
        bv01 = *(const bf16x8*)(vt + kv_bh + (long)(16 + l15) * S_ + kbase + quad * 8);
        bv10 = *(const bf16x8*)(vt + kv_bh + (long)(l15) * S_ + kbase + 32 + quad * 8);
        bv11 = *(const bf16x8*)(vt + kv_bh + (long)(16 + l15) * S_ + kbase + 32 + quad * 8);

        // bias (register shear via bpermute) + online softmax
        #pragma unroll
        for (int r = 0; r < 4; ++r) {
            float tt[5];
            #pragma unroll
            for (int ut = 0; ut < 5; ++ut) tt[ut] = bperm(bidx[r], ctf[ut][r]);
            float s0 = sc[0][r] + (cnd[r] ? tt[1] : tt[0]);
            float s1 = sc[1][r] + (cnd[r] ? tt[2] : tt[1]);
            float s2 = sc[2][r] + (cnd[r] ? tt[3] : tt[2]);
            float s3 = sc[3][r] + (cnd[r] ? tt[4] : tt[3]);
            float mx = fmaxf(fmaxf(s0, s1), fmaxf(s2, s3));
            mx = fmaxf(mx, __shfl_xor(mx, 1, 64));
            mx = fmaxf(mx, __shfl_xor(mx, 2, 64));
            mx = fmaxf(mx, __shfl_xor(mx, 4, 64));
            mx = fmaxf(mx, __shfl_xor(mx, 8, 64));
            float mnew = fmaxf(m4[r], mx);
            float alpha = __expf(m4[r] - mnew);
            m4[r] = mnew;
            u64 mw = mrow[r * 16 + c] >> l15;
            unsigned lo = (unsigned)mw, hi = (unsigned)(mw >> 32);
            float p0 = __expf(s0 - mnew); p0 = (lo & 1u)         ? p0 : 0.f;
            float p1 = __expf(s1 - mnew); p1 = ((lo >> 16) & 1u) ? p1 : 0.f;
            float p2 = __expf(s2 - mnew); p2 = (hi & 1u)         ? p2 : 0.f;
            float p3 = __expf(s3 - mnew); p3 = ((hi >> 16) & 1u) ? p3 : 0.f;
            l4[r] = l4[r] * alpha + (p0 + p1 + p2 + p3);
            oacc[0][r] *= alpha;
            oacc[1][r] *= alpha;
            u64 pv = ((u64)pk_trunc(p2, p3) << 32) | (u64)pk_trunc(p0, p1);
            *(u64*)(pwbuf + (quad * 4 + r) * 72 + l15 * 4) = pv;
        }
        asm volatile("" ::: "memory");                 // P writes stay before P reads
        // read P back as A-fragments (compiler inserts the lgkm wait)
        preg0 = *(const bf16x8*)(pwbuf + l15 * 72 + quad * 8);
        preg1 = *(const bf16x8*)(pwbuf + l15 * 72 + 32 + quad * 8);
    }
    // final PV (chunk 15)
    oacc[0] = __builtin_amdgcn_mfma_f32_16x16x32_bf16(preg0, bv00, oacc[0], 0, 0, 0);
    oacc[1] = __builtin_amdgcn_mfma_f32_16x16x32_bf16(preg0, bv01, oacc[1], 0, 0, 0);
    oacc[0] = __builtin_amdgcn_mfma_f32_16x16x32_bf16(preg1, bv10, oacc[0], 0, 0, 0);
    oacc[1] = __builtin_amdgcn_mfma_f32_16x16x32_bf16(preg1, bv11, oacc[1], 0, 0, 0);

    #pragma unroll
    for (int r = 0; r < 4; ++r) {
        float l = l4[r];
        l += __shfl_xor(l, 1, 64);
        l += __shfl_xor(l, 2, 64);
        l += __shfl_xor(l, 4, 64);
        l += __shfl_xor(l, 8, 64);
        float inv = 1.0f / l;
        int row = q0 + quad * 4 + r;
        #pragma unroll
        for (int dt = 0; dt < 2; ++dt)
            ao[((long)(b * S_ + row) * H_ + h) * D_ + dt * 16 + l15] = f2b(oacc[dt][r] * inv);
    }
}

extern "C" void kernel_launch(void* const* d_in, const int* in_sizes, int n_in,
                              void* d_out, int out_size, void* d_ws, size_t ws_size,
                              hipStream_t stream) {
    (void)in_sizes; (void)n_in; (void)out_size; (void)ws_size;
    const float* kv   = (const float*)d_in[0];
    const float* q    = (const float*)d_in[1];
    const int*   mask = (const int*)d_in[2];
    const float* Wq   = (const float*)d_in[3];
    const float* Wk   = (const float*)d_in[4];
    const float* Wv   = (const float*)d_in[5];
    const float* Wo   = (const float*)d_in[6];
    const float* rt   = (const float*)d_in[7];
    const float* Wrel = (const float*)d_in[8];

    // workspace map — 18.75 MB total (proven-safe envelope is >= 20.75 MB)
    char* ws = (char*)d_ws;
    short* qh   = (short*)(ws);                      // [B,H,S,D] bf16, 4MB
    short* kh   = (short*)(ws + (4u  << 20));        // [B,H,S,D] 4MB
    short* vt   = (short*)(ws + (8u  << 20));        // [B,H,D,S'] k-permuted, 4MB
    short* ao   = (short*)(ws + (12u << 20));        // [B,S,H,D] 4MB
    short* Wt   = (short*)(ws + (16u << 20));        // 4x[512n][512k] bf16, 2MB
    short* relb = (short*)(ws + (18u << 20));        // [2049,32] bf16, 128KB
    u64*  mbits = (u64*) (ws + (18u << 20) + (256u << 10));  // 512KB

    const float scale = 0.17677669529663687f;        // 1/sqrt(32) folded into QH (and thus QR)

    prep_kernel<<<257 + 4096 + 1024, 256, 0, stream>>>(
        rt, relb, mask, mbits, Wq, Wk, Wv, Wo, Wt);

    gemm3_kernel<<<1536, 256, 0, stream>>>(q, kv, Wt, qh, kh, vt, scale);

    attn_kernel<<<1024, 256, 0, stream>>>(qh, Wrel, kh, vt, relb, mbits, ao);

    gemm_out_kernel<<<512, 256, 0, stream>>>(ao, Wt, (float*)d_out);
}